// Round 6
// baseline (1737.676 us; speedup 1.0000x reference)
//
#include <hip/hip_runtime.h>
#include <hip/hip_bf16.h>

#define NN 50000
#define EE 800000
#define DD 128

typedef __attribute__((ext_vector_type(8))) short bf16x8;
typedef __attribute__((ext_vector_type(4))) float f32x4;

__device__ __forceinline__ short f2bf(float f) {
    __hip_bfloat16 h = __float2bfloat16(f);
    return __builtin_bit_cast(short, h);
}

__device__ __forceinline__ float bf2f(short s) {
    unsigned int u = ((unsigned int)(unsigned short)s) << 16;
    return __builtin_bit_cast(float, u);
}

__device__ __forceinline__ float fast_silu(float x) {
    return x / (1.0f + __expf(-x));
}

// ---- prep_all: blocks [0,6250): h->bf16, zero agg, receiver histogram.
//      blocks [6250,6635): pack 6 weight blocks into MFMA B-frag order + w1c. ----
__global__ void prep_all_kernel(const float* __restrict__ h, unsigned short* __restrict__ hp,
                                float4* __restrict__ agg4, const int* __restrict__ ei,
                                int* __restrict__ cnt,
                                const float* __restrict__ W1, const float* __restrict__ W2,
                                const float* __restrict__ U1, const float* __restrict__ U2,
                                unsigned short* __restrict__ packs,
                                float* __restrict__ w1c_out) {
    if (blockIdx.x < 6250) {
        int t = blockIdx.x * blockDim.x + threadIdx.x;   // 1.6M threads exactly
        float4 v = ((const float4*)h)[t];
        ushort4 o;
        o.x = (unsigned short)f2bf(v.x);
        o.y = (unsigned short)f2bf(v.y);
        o.z = (unsigned short)f2bf(v.z);
        o.w = (unsigned short)f2bf(v.w);
        ((ushort4*)hp)[t] = o;
        agg4[t] = make_float4(0.f, 0.f, 0.f, 0.f);       // 6.4M floats exactly
        if (t < EE) atomicAdd(&cnt[ei[EE + t]], 1);      // receiver histogram
        return;
    }
    int t = (blockIdx.x - 6250) * blockDim.x + threadIdx.x;
    if (t >= 98304) {
        if (t < 98432) { int d = t - 98304; w1c_out[d] = W1[d * 257 + 256]; }
        return;
    }
    int mat = t >> 14;
    int r = t & 16383;
    int j = r & 7;
    int lane = (r >> 3) & 63;
    int f = r >> 9;            // 0..31
    int ks = f & 3, nt = f >> 2;
    int n = nt * 16 + (lane & 15);
    int k = ks * 32 + (lane >> 4) * 8 + j;
    float v;
    switch (mat) {
        case 0: v = W1[n * 257 + k];        break;  // W1a (vs h_sender)
        case 1: v = W1[n * 257 + 128 + k];  break;  // W1b (vs h_receiver)
        case 2: v = W2[n * 128 + k];        break;  // W2
        case 3: v = U1[n * 256 + k];        break;  // U1a (vs h)
        case 4: v = U1[n * 256 + 128 + k];  break;  // U1b (vs agg)
        default: v = U2[n * 128 + k];       break;  // U2
    }
    packs[t] = (unsigned short)f2bf(v);
}

// ---- scan: stripe-ownership exclusive scan, coalesced; writes off[] AND cursor[] ----
__global__ void scan_kernel(const int* __restrict__ cnt, int* __restrict__ off,
                            int* __restrict__ cursor) {
    __shared__ int part[1024];
    const int t = threadIdx.x;
    int s = 0;
    #pragma unroll
    for (int j = 0; j < 49; j++) {
        int i = j * 1024 + t;                        // coalesced
        if (i < NN) s += cnt[i];
    }
    part[t] = s;
    __syncthreads();
    for (int d = 1; d < 1024; d <<= 1) {
        int v = (t >= d) ? part[t - d] : 0;
        __syncthreads();
        part[t] += v;
        __syncthreads();
    }
    int base = (t == 0) ? 0 : part[t - 1];
    #pragma unroll
    for (int j = 0; j < 49; j++) {
        int i = j * 1024 + t;                        // coalesced
        if (i < NN) {
            off[i] = base;
            cursor[i] = base;
            base += cnt[i];
        }
    }
}

// NOTE: stripe scan assigns buckets in stripe order, NOT ascending receiver order.
// Receiver ownership per wave only needs each receiver's edges CONTIGUOUS with
// known [off[r], off[r]+cnt[r]) — ascending order across receivers is NOT
// required for correctness of wave ownership, but waves own receivers 4g..4g+3
// whose buckets are disjoint ranges; contiguity per receiver is what matters.
// However the per-wave edge range [off[4g], off[4g+4]) is only valid if buckets
// of r, r+1, r+2, r+3 are consecutive in memory. Stripe order breaks that!
// => wave must process its 4 receivers as 4 independent bucket ranges.
// (Handled below: per-receiver segments via off[r]/cnt-free boundaries read
// from off[] per receiver.)

// ---- prep_g (blocks [0,782)) + scatter (blocks [782,3907)) ----
__global__ __launch_bounds__(256, 2) void prep_g_scatter_kernel(
    const unsigned short* __restrict__ hp,
    const bf16x8* __restrict__ w1a_pack,
    const bf16x8* __restrict__ w1b_pack,
    const float* __restrict__ b1,
    unsigned short* __restrict__ G,
    const int* __restrict__ ei,
    int* __restrict__ cursor,
    int2* __restrict__ ssr)
{
    if (blockIdx.x >= 782) {
        // scatter edges into receiver-bucketed order
        int e = (blockIdx.x - 782) * 256 + threadIdx.x;   // 3125*256 = 800000 exactly
        int s = ei[e], r = ei[EE + e];
        int pos = atomicAdd(&cursor[r], 1);
        ssr[pos] = make_int2(s, r);
        return;
    }
    const int tid = threadIdx.x;
    const int wave = tid >> 6, lane = tid & 63;
    const int quad = lane >> 4, l15 = lane & 15;
    const int nbase = blockIdx.x * 64 + wave * 16;

    int n = nbase + l15;
    int nrow = n < NN ? n : NN - 1;

    bf16x8 ah[4];
    #pragma unroll
    for (int ks = 0; ks < 4; ks++)
        ah[ks] = *(const bf16x8*)(hp + (size_t)nrow * DD + ks * 32 + quad * 8);

    f32x4 acca[8], accb[8];
    #pragma unroll
    for (int nt = 0; nt < 8; nt++) {
        acca[nt] = f32x4{0.f, 0.f, 0.f, 0.f};
        accb[nt] = f32x4{0.f, 0.f, 0.f, 0.f};
    }

    #pragma unroll
    for (int ks = 0; ks < 4; ks++) {
        #pragma unroll
        for (int nt = 0; nt < 8; nt++)
            acca[nt] = __builtin_amdgcn_mfma_f32_16x16x32_bf16(
                ah[ks], w1a_pack[(nt * 4 + ks) * 64 + lane], acca[nt], 0, 0, 0);
        #pragma unroll
        for (int nt = 0; nt < 8; nt++)
            accb[nt] = __builtin_amdgcn_mfma_f32_16x16x32_bf16(
                ah[ks], w1b_pack[(nt * 4 + ks) * 64 + lane], accb[nt], 0, 0, 0);
    }

    #pragma unroll
    for (int nt = 0; nt < 8; nt++) {
        int d = nt * 16 + l15;
        float b1v = b1[d];
        #pragma unroll
        for (int r = 0; r < 4; r++) {
            int n2 = nbase + quad * 4 + r;
            if (n2 < NN) {
                G[(size_t)n2 * 256 + d]       = (unsigned short)f2bf(acca[nt][r] + b1v);
                G[(size_t)n2 * 256 + 128 + d] = (unsigned short)f2bf(accb[nt][r]);
            }
        }
    }
}

// ---- edge kernel v4: WAVE OWNS RECEIVERS. Wave g handles receivers 4g..4g+3;
//      each receiver's edges are a contiguous bucket [off[r], off[r]+len).
//      Segmented in-register reduce, carry across 16-row tiles, flush with
//      PLAIN STORES only. ZERO global atomics. ----
__global__ __launch_bounds__(256, 4) void edge_kernel(
    const unsigned short* __restrict__ G,      // [NN][256] bf16: [G1a+b1 | G1b]
    const float* __restrict__ coords,          // [NN][3]
    const int2* __restrict__ ssr,              // [EE] (send, recv), receiver-bucketed
    const int* __restrict__ off,               // [NN] bucket starts
    const bf16x8* __restrict__ w2_pack,        // 32 KB
    const float* __restrict__ w1c,             // [128] fp32, k-order
    const float* __restrict__ b2,
    float* __restrict__ agg)                   // [NN][128] fp32, pre-zeroed
{
    __shared__ float w1c_s[4][128];
    __shared__ int eoff_s[4][5];               // per-wave: bucket bounds of its 4 receivers

    const int tid = threadIdx.x;
    const int wave = tid >> 6, lane = tid & 63;
    const int quad = lane >> 4, l15 = lane & 15;

    const int g = blockIdx.x * 4 + wave;       // 0..12499
    const int r0 = g * 4;

    w1c_s[wave][lane] = w1c[lane];
    w1c_s[wave][64 + lane] = w1c[64 + lane];

    float b2f[8];
    #pragma unroll
    for (int nt = 0; nt < 8; nt++) b2f[nt] = b2[nt * 16 + l15];

    // Buckets are contiguous per receiver but NOT ordered across receivers
    // (stripe scan). Wave processes its 4 receivers sequentially; receivers
    // 4g..4g+3 ARE stripe-adjacent only when owned by the same scan thread.
    // Since 4g..4g+3 map to scan indices i with the same stripe thread iff
    // they share (i mod 1024)... not guaranteed. So: process each receiver's
    // bucket independently. Within a bucket all rows share one receiver ->
    // no ballot needed at all; pure accumulate + one store per receiver.
    if (lane < 4) eoff_s[wave][lane] = off[r0 + lane];
    if (lane == 4) {
        // bucket length of r0+3 needs cnt; recover from cursor-free scheme:
        // off[r]+len is NOT off[r+1] under stripe order. Store end via cnt-less
        // trick: scatter bumped cursor[r] to off[r]+len; read cursor instead.
        // (cursor passed via off+NN alias; see launch: off2 = cursor array)
    }
    asm volatile("s_waitcnt lgkmcnt(0)" ::: "memory");

    #pragma unroll 1
    for (int rr = 0; rr < 4; rr++) {
        const int rnode = r0 + rr;
        const int eA = eoff_s[wave][rr];
        const int eB = off[NN + rnode];        // cursor[rnode] = bucket end (post-scatter)
        if (eA >= eB) continue;                // empty receiver: row stays zero

        // receiver-side data: uniform for the whole bucket
        bf16x8 gb[4];
        #pragma unroll
        for (int ks = 0; ks < 4; ks++)
            gb[ks] = *(const bf16x8*)(G + (size_t)rnode * 256 + 128 + ks * 32 + quad * 8);
        float rx = coords[3 * rnode + 0];
        float ry = coords[3 * rnode + 1];
        float rz = coords[3 * rnode + 2];

        // prologue: tile-0 sender loads
        int e0 = eA + l15;
        int s_cur = ssr[e0 < eB ? e0 : eB - 1].x;
        bf16x8 ga[4];
        #pragma unroll
        for (int ks = 0; ks < 4; ks++)
            ga[ks] = *(const bf16x8*)(G + (size_t)s_cur * 256 + ks * 32 + quad * 8);
        float sx = coords[3 * s_cur + 0];
        float sy = coords[3 * s_cur + 1];
        float sz = coords[3 * s_cur + 2];

        float acc[8];
        #pragma unroll
        for (int nt = 0; nt < 8; nt++) acc[nt] = 0.f;

        for (int te = eA; te < eB; te += 16) {
            float dx = sx - rx, dy = sy - ry, dz = sz - rz;
            float dist = sqrtf(dx * dx + dy * dy + dz * dz);

            // layer-1 epilogue in A-frag layout (w1c from LDS, quad-broadcast)
            bf16x8 m1f[4];
            #pragma unroll
            for (int ks = 0; ks < 4; ks++) {
                f32x4 c0 = *(const f32x4*)&w1c_s[wave][ks * 32 + quad * 8];
                f32x4 c1 = *(const f32x4*)&w1c_s[wave][ks * 32 + quad * 8 + 4];
                #pragma unroll
                for (int j = 0; j < 4; j++) {
                    float pre0 = bf2f(ga[ks][j])     + bf2f(gb[ks][j])     + dist * c0[j];
                    float pre1 = bf2f(ga[ks][4 + j]) + bf2f(gb[ks][4 + j]) + dist * c1[j];
                    m1f[ks][j]     = f2bf(fast_silu(pre0));
                    m1f[ks][4 + j] = f2bf(fast_silu(pre1));
                }
            }

            // prefetch next tile's sender data
            if (te + 16 < eB) {
                int e2 = te + 16 + l15;
                s_cur = ssr[e2 < eB ? e2 : eB - 1].x;
                #pragma unroll
                for (int ks = 0; ks < 4; ks++)
                    ga[ks] = *(const bf16x8*)(G + (size_t)s_cur * 256 + ks * 32 + quad * 8);
                sx = coords[3 * s_cur + 0];
                sy = coords[3 * s_cur + 1];
                sz = coords[3 * s_cur + 2];
            }

            // layer 2: W2 MFMA
            f32x4 sv[8];
            #pragma unroll
            for (int nt = 0; nt < 8; nt++) sv[nt] = f32x4{0.f, 0.f, 0.f, 0.f};
            #pragma unroll
            for (int ks = 0; ks < 4; ks++)
                #pragma unroll
                for (int nt = 0; nt < 8; nt++)
                    sv[nt] = __builtin_amdgcn_mfma_f32_16x16x32_bf16(
                        m1f[ks], w2_pack[(nt * 4 + ks) * 64 + lane], sv[nt], 0, 0, 0);

            // silu + masked row accumulate (row = quad*4+r, valid if te+row < eB)
            #pragma unroll
            for (int nt = 0; nt < 8; nt++) {
                #pragma unroll
                for (int r = 0; r < 4; r++) {
                    float v = fast_silu(sv[nt][r] + b2f[nt]);
                    acc[nt] += (te + quad * 4 + r < eB) ? v : 0.f;
                }
            }
        }

        // cross-quad reduce and single plain store of the receiver row
        #pragma unroll
        for (int nt = 0; nt < 8; nt++) {
            float s = acc[nt];
            s += __shfl_xor(s, 16);
            s += __shfl_xor(s, 32);
            acc[nt] = s;
        }
        size_t base = (size_t)rnode * DD + l15;
        agg[base + (quad * 2 + 0) * 16] = acc[quad * 2 + 0];
        agg[base + (quad * 2 + 1) * 16] = acc[quad * 2 + 1];
    }
}

// ---- node kernel: out = h + U2*silu(U1a*h + U1b*agg + c1) + c2 ----
__global__ __launch_bounds__(256, 4) void node_kernel(
    const unsigned short* __restrict__ hp,
    const float* __restrict__ hf,
    const float* __restrict__ agg,
    const bf16x8* __restrict__ u1a_pack,
    const bf16x8* __restrict__ u1b_pack,
    const bf16x8* __restrict__ u2_pack,
    const float* __restrict__ c1,
    const float* __restrict__ c2,
    float* __restrict__ out)
{
    __shared__ unsigned short u1s[4][16][136];

    const int tid = threadIdx.x;
    const int wave = tid >> 6, lane = tid & 63;
    const int quad = lane >> 4, l15 = lane & 15;
    const int nbase = blockIdx.x * 64 + wave * 16;

    int n = nbase + l15;
    int nrow = n < NN ? n : NN - 1;

    float c1v[8];
    #pragma unroll
    for (int nt = 0; nt < 8; nt++) c1v[nt] = c1[nt * 16 + l15];

    bf16x8 ah[4], ag[4];
    #pragma unroll
    for (int ks = 0; ks < 4; ks++) {
        ah[ks] = *(const bf16x8*)(hp + (size_t)nrow * DD + ks * 32 + quad * 8);
        const float* ap = agg + (size_t)nrow * DD + ks * 32 + quad * 8;
        f32x4 g0 = *(const f32x4*)ap;
        f32x4 g1 = *(const f32x4*)(ap + 4);
        bf16x8 t;
        t[0] = f2bf(g0[0]); t[1] = f2bf(g0[1]); t[2] = f2bf(g0[2]); t[3] = f2bf(g0[3]);
        t[4] = f2bf(g1[0]); t[5] = f2bf(g1[1]); t[6] = f2bf(g1[2]); t[7] = f2bf(g1[3]);
        ag[ks] = t;
    }

    f32x4 acc[8];
    #pragma unroll
    for (int nt = 0; nt < 8; nt++) acc[nt] = f32x4{0.f, 0.f, 0.f, 0.f};

    #pragma unroll
    for (int ks = 0; ks < 4; ks++) {
        #pragma unroll
        for (int nt = 0; nt < 8; nt++)
            acc[nt] = __builtin_amdgcn_mfma_f32_16x16x32_bf16(
                ah[ks], u1a_pack[(nt * 4 + ks) * 64 + lane], acc[nt], 0, 0, 0);
        #pragma unroll
        for (int nt = 0; nt < 8; nt++)
            acc[nt] = __builtin_amdgcn_mfma_f32_16x16x32_bf16(
                ag[ks], u1b_pack[(nt * 4 + ks) * 64 + lane], acc[nt], 0, 0, 0);
    }

    #pragma unroll
    for (int nt = 0; nt < 8; nt++) {
        int d = nt * 16 + l15;
        #pragma unroll
        for (int r = 0; r < 4; r++) {
            float pre = acc[nt][r] + c1v[nt];
            u1s[wave][quad * 4 + r][d] = (unsigned short)f2bf(fast_silu(pre));
        }
    }
    asm volatile("s_waitcnt lgkmcnt(0)" ::: "memory");

    bf16x8 a2[4];
    #pragma unroll
    for (int ks = 0; ks < 4; ks++)
        a2[ks] = *(const bf16x8*)(&u1s[wave][l15][ks * 32 + quad * 8]);

    f32x4 acc2[8];
    #pragma unroll
    for (int nt = 0; nt < 8; nt++) acc2[nt] = f32x4{0.f, 0.f, 0.f, 0.f};

    #pragma unroll
    for (int ks = 0; ks < 4; ks++)
        #pragma unroll
        for (int nt = 0; nt < 8; nt++)
            acc2[nt] = __builtin_amdgcn_mfma_f32_16x16x32_bf16(
                a2[ks], u2_pack[(nt * 4 + ks) * 64 + lane], acc2[nt], 0, 0, 0);

    #pragma unroll
    for (int nt = 0; nt < 8; nt++) {
        int d = nt * 16 + l15;
        float c2v = c2[d];
        #pragma unroll
        for (int r = 0; r < 4; r++) {
            int n2 = nbase + quad * 4 + r;
            if (n2 < NN) {
                size_t idx = (size_t)n2 * DD + d;
                out[idx] = hf[idx] + acc2[nt][r] + c2v;
            }
        }
    }
}

extern "C" void kernel_launch(void* const* d_in, const int* in_sizes, int n_in,
                              void* d_out, int out_size, void* d_ws, size_t ws_size,
                              hipStream_t stream) {
    const float* h      = (const float*)d_in[0];
    const float* coords = (const float*)d_in[1];
    const int* ei       = (const int*)d_in[2];   // int64 in reference -> int32 from harness
    const float* W1 = (const float*)d_in[3];
    const float* b1 = (const float*)d_in[4];
    const float* W2 = (const float*)d_in[5];
    const float* b2 = (const float*)d_in[6];
    const float* U1 = (const float*)d_in[7];
    const float* c1 = (const float*)d_in[8];
    const float* U2 = (const float*)d_in[9];
    const float* c2 = (const float*)d_in[10];
    float* out = (float*)d_out;

    char* ws = (char*)d_ws;
    float* agg            = (float*)ws;                          // 25,600,000 B fp32 [NN][128]
    unsigned short* hp    = (unsigned short*)(ws + 25600000);    // 12,800,000 B bf16 h
    unsigned short* packs = (unsigned short*)(ws + 38400000);    //    196,608 B packed weights
    float* w1c            = (float*)(ws + 38600000);             //        512 B
    unsigned short* G     = (unsigned short*)(ws + 38700000);    // 25,600,000 B bf16 [NN][256]
    int* cnt              = (int*)(ws + 64300000);               //    200,000 B
    int* offcur           = (int*)(ws + 64500000);               //    400,000 B: [0,NN)=off, [NN,2NN)=cursor
    int2* ssr             = (int2*)(ws + 64900000);              //  6,400,000 B sorted (s,r)
    const bf16x8* w1a = (const bf16x8*)(packs);
    const bf16x8* w1b = (const bf16x8*)(packs + 16384);
    const bf16x8* w2p = (const bf16x8*)(packs + 32768);
    const bf16x8* u1a = (const bf16x8*)(packs + 49152);
    const bf16x8* u1b = (const bf16x8*)(packs + 65536);
    const bf16x8* u2p = (const bf16x8*)(packs + 81920);

    hipMemsetAsync(cnt, 0, NN * sizeof(int), stream);
    prep_all_kernel<<<6635, 256, 0, stream>>>(h, hp, (float4*)agg, ei, cnt,
                                              W1, W2, U1, U2, packs, w1c);
    scan_kernel<<<1, 1024, 0, stream>>>(cnt, offcur, offcur + NN);
    prep_g_scatter_kernel<<<3907, 256, 0, stream>>>(hp, w1a, w1b, b1, G, ei,
                                                    offcur + NN, ssr);
    // edge: 3125 blocks * 4 waves * 4 receivers = 50000 receivers
    edge_kernel<<<3125, 256, 0, stream>>>(G, coords, ssr, offcur, w2p, w1c, b2, agg);
    node_kernel<<<(NN + 63) / 64, 256, 0, stream>>>(hp, h, agg, u1a, u1b, u2p, c1, c2, out);
}

// Round 7
// 1020.654 us; speedup vs baseline: 1.7025x; 1.7025x over previous
//
#include <hip/hip_runtime.h>
#include <hip/hip_bf16.h>

#define NN 50000
#define EE 800000
#define DD 128

typedef __attribute__((ext_vector_type(8))) short bf16x8;
typedef __attribute__((ext_vector_type(4))) float f32x4;

__device__ __forceinline__ short f2bf(float f) {
    __hip_bfloat16 h = __float2bfloat16(f);
    return __builtin_bit_cast(short, h);
}

__device__ __forceinline__ float bf2f(short s) {
    unsigned int u = ((unsigned int)(unsigned short)s) << 16;
    return __builtin_bit_cast(float, u);
}

__device__ __forceinline__ float fast_silu(float x) {
    return x / (1.0f + __expf(-x));
}

// ---- prep_all: blocks [0,6250): h->bf16 + receiver histogram.
//      blocks [6250,6635): pack 6 weight blocks into MFMA B-frag order + w1c. ----
__global__ void prep_all_kernel(const float* __restrict__ h, unsigned short* __restrict__ hp,
                                const int* __restrict__ ei, int* __restrict__ cnt,
                                const float* __restrict__ W1, const float* __restrict__ W2,
                                const float* __restrict__ U1, const float* __restrict__ U2,
                                unsigned short* __restrict__ packs,
                                float* __restrict__ w1c_out) {
    if (blockIdx.x < 6250) {
        int t = blockIdx.x * blockDim.x + threadIdx.x;   // 1.6M threads exactly
        float4 v = ((const float4*)h)[t];
        ushort4 o;
        o.x = (unsigned short)f2bf(v.x);
        o.y = (unsigned short)f2bf(v.y);
        o.z = (unsigned short)f2bf(v.z);
        o.w = (unsigned short)f2bf(v.w);
        ((ushort4*)hp)[t] = o;
        if (t < EE) atomicAdd(&cnt[ei[EE + t]], 1);      // receiver histogram
        return;
    }
    int t = (blockIdx.x - 6250) * blockDim.x + threadIdx.x;
    if (t >= 98304) {
        if (t < 98432) { int d = t - 98304; w1c_out[d] = W1[d * 257 + 256]; }
        return;
    }
    int mat = t >> 14;
    int r = t & 16383;
    int j = r & 7;
    int lane = (r >> 3) & 63;
    int f = r >> 9;            // 0..31
    int ks = f & 3, nt = f >> 2;
    int n = nt * 16 + (lane & 15);
    int k = ks * 32 + (lane >> 4) * 8 + j;
    float v;
    switch (mat) {
        case 0: v = W1[n * 257 + k];        break;  // W1a (vs h_sender)
        case 1: v = W1[n * 257 + 128 + k];  break;  // W1b (vs h_receiver)
        case 2: v = W2[n * 128 + k];        break;  // W2
        case 3: v = U1[n * 256 + k];        break;  // U1a (vs h)
        case 4: v = U1[n * 256 + 128 + k];  break;  // U1b (vs agg)
        default: v = U2[n * 128 + k];       break;  // U2
    }
    packs[t] = (unsigned short)f2bf(v);
}

// ---- scan: stripe-ownership exclusive scan, coalesced; writes off[] AND cursor[] ----
// Bucket order across receivers is stripe order (arbitrary) — irrelevant: each
// receiver's bucket [off[r], end[r]) is contiguous, and the edge kernel processes
// each receiver's bucket independently.
__global__ void scan_kernel(const int* __restrict__ cnt, int* __restrict__ off,
                            int* __restrict__ cursor) {
    __shared__ int part[1024];
    const int t = threadIdx.x;
    int s = 0;
    #pragma unroll
    for (int j = 0; j < 49; j++) {
        int i = j * 1024 + t;                        // coalesced
        if (i < NN) s += cnt[i];
    }
    part[t] = s;
    __syncthreads();
    for (int d = 1; d < 1024; d <<= 1) {
        int v = (t >= d) ? part[t - d] : 0;
        __syncthreads();
        part[t] += v;
        __syncthreads();
    }
    int base = (t == 0) ? 0 : part[t - 1];
    #pragma unroll
    for (int j = 0; j < 49; j++) {
        int i = j * 1024 + t;                        // coalesced
        if (i < NN) {
            off[i] = base;
            cursor[i] = base;
            base += cnt[i];
        }
    }
}

// ---- prep_g (blocks [0,782)) + scatter-with-dist (blocks [782,3907)) ----
__global__ __launch_bounds__(256, 2) void prep_g_scatter_kernel(
    const unsigned short* __restrict__ hp,
    const bf16x8* __restrict__ w1a_pack,
    const bf16x8* __restrict__ w1b_pack,
    const float* __restrict__ b1,
    unsigned short* __restrict__ G,
    const int* __restrict__ ei,
    const float* __restrict__ coords,
    int* __restrict__ cursor,
    int2* __restrict__ ssr)
{
    if (blockIdx.x >= 782) {
        // scatter edges into receiver buckets; precompute dist here so the edge
        // kernel never touches coords (saves registers + one gather stream).
        int e = (blockIdx.x - 782) * 256 + threadIdx.x;   // 3125*256 = 800000 exactly
        int s = ei[e], r = ei[EE + e];
        float dx = coords[3 * s + 0] - coords[3 * r + 0];
        float dy = coords[3 * s + 1] - coords[3 * r + 1];
        float dz = coords[3 * s + 2] - coords[3 * r + 2];
        float dist = sqrtf(dx * dx + dy * dy + dz * dz);
        int pos = atomicAdd(&cursor[r], 1);
        ssr[pos] = make_int2(s, __builtin_bit_cast(int, dist));
        return;
    }
    const int tid = threadIdx.x;
    const int wave = tid >> 6, lane = tid & 63;
    const int quad = lane >> 4, l15 = lane & 15;
    const int nbase = blockIdx.x * 64 + wave * 16;

    int n = nbase + l15;
    int nrow = n < NN ? n : NN - 1;

    bf16x8 ah[4];
    #pragma unroll
    for (int ks = 0; ks < 4; ks++)
        ah[ks] = *(const bf16x8*)(hp + (size_t)nrow * DD + ks * 32 + quad * 8);

    f32x4 acca[8], accb[8];
    #pragma unroll
    for (int nt = 0; nt < 8; nt++) {
        acca[nt] = f32x4{0.f, 0.f, 0.f, 0.f};
        accb[nt] = f32x4{0.f, 0.f, 0.f, 0.f};
    }

    #pragma unroll
    for (int ks = 0; ks < 4; ks++) {
        #pragma unroll
        for (int nt = 0; nt < 8; nt++)
            acca[nt] = __builtin_amdgcn_mfma_f32_16x16x32_bf16(
                ah[ks], w1a_pack[(nt * 4 + ks) * 64 + lane], acca[nt], 0, 0, 0);
        #pragma unroll
        for (int nt = 0; nt < 8; nt++)
            accb[nt] = __builtin_amdgcn_mfma_f32_16x16x32_bf16(
                ah[ks], w1b_pack[(nt * 4 + ks) * 64 + lane], accb[nt], 0, 0, 0);
    }

    #pragma unroll
    for (int nt = 0; nt < 8; nt++) {
        int d = nt * 16 + l15;
        float b1v = b1[d];
        #pragma unroll
        for (int r = 0; r < 4; r++) {
            int n2 = nbase + quad * 4 + r;
            if (n2 < NN) {
                G[(size_t)n2 * 256 + d]       = (unsigned short)f2bf(acca[nt][r] + b1v);
                G[(size_t)n2 * 256 + 128 + d] = (unsigned short)f2bf(accb[nt][r]);
            }
        }
    }
}

// ---- edge kernel v5: WAVE OWNS RECEIVERS (4 per wave), spill-free.
//      Per receiver: hoist G1b once, stream 16-edge tiles (sender row + precomputed
//      dist from ssr), silu -> W2 MFMA -> masked in-register row-sum.
//      One plain coalesced row store per receiver. ZERO global atomics. ----
__global__ __launch_bounds__(256, 3) void edge_kernel(
    const unsigned short* __restrict__ G,      // [NN][256] bf16: [G1a+b1 | G1b]
    const int2* __restrict__ ssr,              // [EE] (sender, dist_bits), bucketed
    const int* __restrict__ off,               // [2*NN]: starts | ends(=cursor)
    const bf16x8* __restrict__ w2_pack,        // 32 KB
    const float* __restrict__ w1c,             // [128] fp32, k-order
    const float* __restrict__ b2,
    float* __restrict__ agg)                   // [NN][128] fp32 (NOT pre-zeroed)
{
    __shared__ float w1c_s[4][128];

    const int tid = threadIdx.x;
    const int wave = tid >> 6, lane = tid & 63;
    const int quad = lane >> 4, l15 = lane & 15;

    const int g = blockIdx.x * 4 + wave;       // 0..12499
    const int r0 = g * 4;

    w1c_s[wave][lane] = w1c[lane];
    w1c_s[wave][64 + lane] = w1c[64 + lane];
    asm volatile("s_waitcnt lgkmcnt(0)" ::: "memory");   // wave-local LDS only

    float b2f[8];
    #pragma unroll
    for (int nt = 0; nt < 8; nt++) b2f[nt] = b2[nt * 16 + l15];

    #pragma unroll 1
    for (int rr = 0; rr < 4; rr++) {
        const int rnode = r0 + rr;
        const int eA = off[rnode];
        const int eB = off[NN + rnode];        // bucket end (cursor after scatter)

        // receiver-side data: uniform for the whole bucket (L1-broadcast)
        bf16x8 gb[4];
        #pragma unroll
        for (int ks = 0; ks < 4; ks++)
            gb[ks] = *(const bf16x8*)(G + (size_t)rnode * 256 + 128 + ks * 32 + quad * 8);

        float acc[8];
        #pragma unroll
        for (int nt = 0; nt < 8; nt++) acc[nt] = 0.f;

        for (int te = eA; te < eB; te += 16) {
            int p = te + l15;
            int2 sd = ssr[p < eB ? p : eB - 1];          // row l15's (sender, dist)
            float dist = __builtin_bit_cast(float, sd.y);

            bf16x8 ga[4];
            #pragma unroll
            for (int ks = 0; ks < 4; ks++)
                ga[ks] = *(const bf16x8*)(G + (size_t)sd.x * 256 + ks * 32 + quad * 8);

            // layer-1 epilogue in A-frag layout (w1c from LDS, quad-broadcast)
            bf16x8 m1f[4];
            #pragma unroll
            for (int ks = 0; ks < 4; ks++) {
                f32x4 c0 = *(const f32x4*)&w1c_s[wave][ks * 32 + quad * 8];
                f32x4 c1 = *(const f32x4*)&w1c_s[wave][ks * 32 + quad * 8 + 4];
                #pragma unroll
                for (int j = 0; j < 4; j++) {
                    float pre0 = bf2f(ga[ks][j])     + bf2f(gb[ks][j])     + dist * c0[j];
                    float pre1 = bf2f(ga[ks][4 + j]) + bf2f(gb[ks][4 + j]) + dist * c1[j];
                    m1f[ks][j]     = f2bf(fast_silu(pre0));
                    m1f[ks][4 + j] = f2bf(fast_silu(pre1));
                }
            }

            // layer 2: W2 MFMA
            f32x4 sv[8];
            #pragma unroll
            for (int nt = 0; nt < 8; nt++) sv[nt] = f32x4{0.f, 0.f, 0.f, 0.f};
            #pragma unroll
            for (int ks = 0; ks < 4; ks++)
                #pragma unroll
                for (int nt = 0; nt < 8; nt++)
                    sv[nt] = __builtin_amdgcn_mfma_f32_16x16x32_bf16(
                        m1f[ks], w2_pack[(nt * 4 + ks) * 64 + lane], sv[nt], 0, 0, 0);

            // silu + masked row accumulate (C row = quad*4+r <-> edge te+quad*4+r)
            #pragma unroll
            for (int nt = 0; nt < 8; nt++) {
                #pragma unroll
                for (int r = 0; r < 4; r++) {
                    float v = fast_silu(sv[nt][r] + b2f[nt]);
                    acc[nt] += (te + quad * 4 + r < eB) ? v : 0.f;
                }
            }
        }

        // cross-quad reduce; single plain coalesced store of the receiver row
        // (empty buckets store zeros — agg is not pre-zeroed)
        #pragma unroll
        for (int nt = 0; nt < 8; nt++) {
            float s = acc[nt];
            s += __shfl_xor(s, 16);
            s += __shfl_xor(s, 32);
            acc[nt] = s;
        }
        size_t base = (size_t)rnode * DD + l15;
        agg[base + (quad * 2 + 0) * 16] = acc[quad * 2 + 0];
        agg[base + (quad * 2 + 1) * 16] = acc[quad * 2 + 1];
    }
}

// ---- node kernel: out = h + U2*silu(U1a*h + U1b*agg + c1) + c2 ----
__global__ __launch_bounds__(256, 4) void node_kernel(
    const unsigned short* __restrict__ hp,
    const float* __restrict__ hf,
    const float* __restrict__ agg,
    const bf16x8* __restrict__ u1a_pack,
    const bf16x8* __restrict__ u1b_pack,
    const bf16x8* __restrict__ u2_pack,
    const float* __restrict__ c1,
    const float* __restrict__ c2,
    float* __restrict__ out)
{
    __shared__ unsigned short u1s[4][16][136];

    const int tid = threadIdx.x;
    const int wave = tid >> 6, lane = tid & 63;
    const int quad = lane >> 4, l15 = lane & 15;
    const int nbase = blockIdx.x * 64 + wave * 16;

    int n = nbase + l15;
    int nrow = n < NN ? n : NN - 1;

    float c1v[8];
    #pragma unroll
    for (int nt = 0; nt < 8; nt++) c1v[nt] = c1[nt * 16 + l15];

    bf16x8 ah[4], ag[4];
    #pragma unroll
    for (int ks = 0; ks < 4; ks++) {
        ah[ks] = *(const bf16x8*)(hp + (size_t)nrow * DD + ks * 32 + quad * 8);
        const float* ap = agg + (size_t)nrow * DD + ks * 32 + quad * 8;
        f32x4 g0 = *(const f32x4*)ap;
        f32x4 g1 = *(const f32x4*)(ap + 4);
        bf16x8 t;
        t[0] = f2bf(g0[0]); t[1] = f2bf(g0[1]); t[2] = f2bf(g0[2]); t[3] = f2bf(g0[3]);
        t[4] = f2bf(g1[0]); t[5] = f2bf(g1[1]); t[6] = f2bf(g1[2]); t[7] = f2bf(g1[3]);
        ag[ks] = t;
    }

    f32x4 acc[8];
    #pragma unroll
    for (int nt = 0; nt < 8; nt++) acc[nt] = f32x4{0.f, 0.f, 0.f, 0.f};

    #pragma unroll
    for (int ks = 0; ks < 4; ks++) {
        #pragma unroll
        for (int nt = 0; nt < 8; nt++)
            acc[nt] = __builtin_amdgcn_mfma_f32_16x16x32_bf16(
                ah[ks], u1a_pack[(nt * 4 + ks) * 64 + lane], acc[nt], 0, 0, 0);
        #pragma unroll
        for (int nt = 0; nt < 8; nt++)
            acc[nt] = __builtin_amdgcn_mfma_f32_16x16x32_bf16(
                ag[ks], u1b_pack[(nt * 4 + ks) * 64 + lane], acc[nt], 0, 0, 0);
    }

    #pragma unroll
    for (int nt = 0; nt < 8; nt++) {
        int d = nt * 16 + l15;
        #pragma unroll
        for (int r = 0; r < 4; r++) {
            float pre = acc[nt][r] + c1v[nt];
            u1s[wave][quad * 4 + r][d] = (unsigned short)f2bf(fast_silu(pre));
        }
    }
    asm volatile("s_waitcnt lgkmcnt(0)" ::: "memory");

    bf16x8 a2[4];
    #pragma unroll
    for (int ks = 0; ks < 4; ks++)
        a2[ks] = *(const bf16x8*)(&u1s[wave][l15][ks * 32 + quad * 8]);

    f32x4 acc2[8];
    #pragma unroll
    for (int nt = 0; nt < 8; nt++) acc2[nt] = f32x4{0.f, 0.f, 0.f, 0.f};

    #pragma unroll
    for (int ks = 0; ks < 4; ks++)
        #pragma unroll
        for (int nt = 0; nt < 8; nt++)
            acc2[nt] = __builtin_amdgcn_mfma_f32_16x16x32_bf16(
                a2[ks], u2_pack[(nt * 4 + ks) * 64 + lane], acc2[nt], 0, 0, 0);

    #pragma unroll
    for (int nt = 0; nt < 8; nt++) {
        int d = nt * 16 + l15;
        float c2v = c2[d];
        #pragma unroll
        for (int r = 0; r < 4; r++) {
            int n2 = nbase + quad * 4 + r;
            if (n2 < NN) {
                size_t idx = (size_t)n2 * DD + d;
                out[idx] = hf[idx] + acc2[nt][r] + c2v;
            }
        }
    }
}

extern "C" void kernel_launch(void* const* d_in, const int* in_sizes, int n_in,
                              void* d_out, int out_size, void* d_ws, size_t ws_size,
                              hipStream_t stream) {
    const float* h      = (const float*)d_in[0];
    const float* coords = (const float*)d_in[1];
    const int* ei       = (const int*)d_in[2];   // int64 in reference -> int32 from harness
    const float* W1 = (const float*)d_in[3];
    const float* b1 = (const float*)d_in[4];
    const float* W2 = (const float*)d_in[5];
    const float* b2 = (const float*)d_in[6];
    const float* U1 = (const float*)d_in[7];
    const float* c1 = (const float*)d_in[8];
    const float* U2 = (const float*)d_in[9];
    const float* c2 = (const float*)d_in[10];
    float* out = (float*)d_out;

    char* ws = (char*)d_ws;
    float* agg            = (float*)ws;                          // 25,600,000 B fp32 [NN][128]
    unsigned short* hp    = (unsigned short*)(ws + 25600000);    // 12,800,000 B bf16 h
    unsigned short* packs = (unsigned short*)(ws + 38400000);    //    196,608 B packed weights
    float* w1c            = (float*)(ws + 38600000);             //        512 B
    unsigned short* G     = (unsigned short*)(ws + 38700000);    // 25,600,000 B bf16 [NN][256]
    int* cnt              = (int*)(ws + 64300000);               //    200,000 B
    int* offcur           = (int*)(ws + 64500000);               //    400,000 B: [0,NN)=off, [NN,2NN)=end
    int2* ssr             = (int2*)(ws + 64900000);              //  6,400,000 B (sender, dist)
    const bf16x8* w1a = (const bf16x8*)(packs);
    const bf16x8* w1b = (const bf16x8*)(packs + 16384);
    const bf16x8* w2p = (const bf16x8*)(packs + 32768);
    const bf16x8* u1a = (const bf16x8*)(packs + 49152);
    const bf16x8* u1b = (const bf16x8*)(packs + 65536);
    const bf16x8* u2p = (const bf16x8*)(packs + 81920);

    hipMemsetAsync(cnt, 0, NN * sizeof(int), stream);
    prep_all_kernel<<<6635, 256, 0, stream>>>(h, hp, ei, cnt,
                                              W1, W2, U1, U2, packs, w1c);
    scan_kernel<<<1, 1024, 0, stream>>>(cnt, offcur, offcur + NN);
    prep_g_scatter_kernel<<<3907, 256, 0, stream>>>(hp, w1a, w1b, b1, G, ei, coords,
                                                    offcur + NN, ssr);
    // edge: 3125 blocks * 4 waves * 4 receivers = 50000 receivers
    edge_kernel<<<3125, 256, 0, stream>>>(G, ssr, offcur, w2p, w1c, b2, agg);
    node_kernel<<<(NN + 63) / 64, 256, 0, stream>>>(hp, h, agg, u1a, u1b, u2p, c1, c2, out);
}

// Round 8
// 478.412 us; speedup vs baseline: 3.6322x; 2.1334x over previous
//
#include <hip/hip_runtime.h>
#include <hip/hip_bf16.h>

#define NN 50000
#define EE 800000
#define DD 128
#define NTILES_MAX 96880          // 6055 blocks * 16 tiles; >= (EE + 15*NN)/16

typedef __attribute__((ext_vector_type(8))) short bf16x8;
typedef __attribute__((ext_vector_type(4))) float f32x4;

__device__ __forceinline__ short f2bf(float f) {
    __hip_bfloat16 h = __float2bfloat16(f);
    return __builtin_bit_cast(short, h);
}

__device__ __forceinline__ float bf2f(short s) {
    unsigned int u = ((unsigned int)(unsigned short)s) << 16;
    return __builtin_bit_cast(float, u);
}

__device__ __forceinline__ float fast_silu(float x) {
    return x / (1.0f + __expf(-x));
}

// ---- prep_all: blocks [0,6250): h->bf16, zero agg, receiver histogram.
//      blocks [6250,6635): pack 6 weight blocks into MFMA B-frag order + w1c. ----
__global__ void prep_all_kernel(const float* __restrict__ h, unsigned short* __restrict__ hp,
                                float4* __restrict__ agg4, const int* __restrict__ ei,
                                int* __restrict__ cnt,
                                const float* __restrict__ W1, const float* __restrict__ W2,
                                const float* __restrict__ U1, const float* __restrict__ U2,
                                unsigned short* __restrict__ packs,
                                float* __restrict__ w1c_out) {
    if (blockIdx.x < 6250) {
        int t = blockIdx.x * blockDim.x + threadIdx.x;   // 1.6M threads exactly
        float4 v = ((const float4*)h)[t];
        ushort4 o;
        o.x = (unsigned short)f2bf(v.x);
        o.y = (unsigned short)f2bf(v.y);
        o.z = (unsigned short)f2bf(v.z);
        o.w = (unsigned short)f2bf(v.w);
        ((ushort4*)hp)[t] = o;
        agg4[t] = make_float4(0.f, 0.f, 0.f, 0.f);       // 6.4M floats exactly
        if (t < EE) atomicAdd(&cnt[ei[EE + t]], 1);      // receiver histogram
        return;
    }
    int t = (blockIdx.x - 6250) * blockDim.x + threadIdx.x;
    if (t >= 98304) {
        if (t < 98432) { int d = t - 98304; w1c_out[d] = W1[d * 257 + 256]; }
        return;
    }
    int mat = t >> 14;
    int r = t & 16383;
    int j = r & 7;
    int lane = (r >> 3) & 63;
    int f = r >> 9;            // 0..31
    int ks = f & 3, nt = f >> 2;
    int n = nt * 16 + (lane & 15);
    int k = ks * 32 + (lane >> 4) * 8 + j;
    float v;
    switch (mat) {
        case 0: v = W1[n * 257 + k];        break;  // W1a (vs h_sender)
        case 1: v = W1[n * 257 + 128 + k];  break;  // W1b (vs h_receiver)
        case 2: v = W2[n * 128 + k];        break;  // W2
        case 3: v = U1[n * 256 + k];        break;  // U1a (vs h)
        case 4: v = U1[n * 256 + 128 + k];  break;  // U1b (vs agg)
        default: v = U2[n * 128 + k];       break;  // U2
    }
    packs[t] = (unsigned short)f2bf(v);
}

// ---- scan: PADDED exclusive scan (each bucket rounded up to x16) + tile->receiver map.
//      cursor[i] = padded bucket start; trec[tile] = receiver owning that 16-slot tile.
//      Bucket order across receivers is stripe order (arbitrary) — fine. ----
__global__ void scan_kernel(const int* __restrict__ cnt, int* __restrict__ cursor,
                            int* __restrict__ trec) {
    __shared__ int part[1024];
    const int t = threadIdx.x;
    int s = 0;
    for (int j = 0; j < 49; j++) {
        int i = j * 1024 + t;                        // coalesced
        if (i < NN) s += ((cnt[i] + 15) >> 4) << 4;  // padded size
    }
    part[t] = s;
    __syncthreads();
    for (int d = 1; d < 1024; d <<= 1) {
        int v = (t >= d) ? part[t - d] : 0;
        __syncthreads();
        part[t] += v;
        __syncthreads();
    }
    int base = (t == 0) ? 0 : part[t - 1];
    for (int j = 0; j < 49; j++) {
        int i = j * 1024 + t;
        if (i < NN) {
            int c = cnt[i];
            cursor[i] = base;                        // padded bucket start (x16 aligned)
            int tb = base >> 4;
            int ntt = (c + 15) >> 4;                 // tiles for this receiver
            for (int k = 0; k < ntt; k++) trec[tb + k] = i;
            base += ntt << 4;
        }
    }
}

// ---- prep_g (blocks [0,782)) + scatter (blocks [782,3907)) ----
__global__ __launch_bounds__(256, 2) void prep_g_scatter_kernel(
    const unsigned short* __restrict__ hp,
    const bf16x8* __restrict__ w1a_pack,
    const bf16x8* __restrict__ w1b_pack,
    const float* __restrict__ b1,
    unsigned short* __restrict__ G,
    const int* __restrict__ ei,
    int* __restrict__ cursor,
    int* __restrict__ ssr)
{
    if (blockIdx.x >= 782) {
        // scatter sender ids into padded receiver buckets (4B random RMW)
        int e = (blockIdx.x - 782) * 256 + threadIdx.x;   // 3125*256 = 800000 exactly
        int s = ei[e], r = ei[EE + e];
        int pos = atomicAdd(&cursor[r], 1);
        ssr[pos] = s;
        return;
    }
    const int tid = threadIdx.x;
    const int wave = tid >> 6, lane = tid & 63;
    const int quad = lane >> 4, l15 = lane & 15;
    const int nbase = blockIdx.x * 64 + wave * 16;

    int n = nbase + l15;
    int nrow = n < NN ? n : NN - 1;

    bf16x8 ah[4];
    #pragma unroll
    for (int ks = 0; ks < 4; ks++)
        ah[ks] = *(const bf16x8*)(hp + (size_t)nrow * DD + ks * 32 + quad * 8);

    f32x4 acca[8], accb[8];
    #pragma unroll
    for (int nt = 0; nt < 8; nt++) {
        acca[nt] = f32x4{0.f, 0.f, 0.f, 0.f};
        accb[nt] = f32x4{0.f, 0.f, 0.f, 0.f};
    }

    #pragma unroll
    for (int ks = 0; ks < 4; ks++) {
        #pragma unroll
        for (int nt = 0; nt < 8; nt++)
            acca[nt] = __builtin_amdgcn_mfma_f32_16x16x32_bf16(
                ah[ks], w1a_pack[(nt * 4 + ks) * 64 + lane], acca[nt], 0, 0, 0);
        #pragma unroll
        for (int nt = 0; nt < 8; nt++)
            accb[nt] = __builtin_amdgcn_mfma_f32_16x16x32_bf16(
                ah[ks], w1b_pack[(nt * 4 + ks) * 64 + lane], accb[nt], 0, 0, 0);
    }

    #pragma unroll
    for (int nt = 0; nt < 8; nt++) {
        int d = nt * 16 + l15;
        float b1v = b1[d];
        #pragma unroll
        for (int r = 0; r < 4; r++) {
            int n2 = nbase + quad * 4 + r;
            if (n2 < NN) {
                G[(size_t)n2 * 256 + d]       = (unsigned short)f2bf(acca[nt][r] + b1v);
                G[(size_t)n2 * 256 + 128 + d] = (unsigned short)f2bf(accb[nt][r]);
            }
        }
    }
}

// ---- edge kernel v7: PADDED-TILE structure. Every 16-edge tile belongs to exactly
//      one receiver (trec map); sentinel slots (-1) masked via ballot. Fully static
//      loops (anti-spill rule: no dynamic-trip MFMA loops). One unconditional
//      full-row atomic flush per tile. ----
__global__ __launch_bounds__(256, 3) void edge_kernel(
    const unsigned short* __restrict__ G,      // [NN][256] bf16: [G1a+b1 | G1b]
    const float* __restrict__ coords,          // [NN][3] (L2-resident, 600 KB)
    const int* __restrict__ ssr,               // [padded slots] sender or -1
    const int* __restrict__ trec,              // [NTILES_MAX] receiver or -1
    const bf16x8* __restrict__ w2_pack,        // 32 KB
    const float* __restrict__ w1c,             // [128] fp32, k-order
    const float* __restrict__ b2,
    float* __restrict__ agg)                   // [NN][128] fp32, pre-zeroed
{
    __shared__ float w1c_s[4][128];

    const int tid = threadIdx.x;
    const int wave = tid >> 6, lane = tid & 63;
    const int quad = lane >> 4, l15 = lane & 15;

    w1c_s[wave][lane] = w1c[lane];
    w1c_s[wave][64 + lane] = w1c[64 + lane];
    asm volatile("s_waitcnt lgkmcnt(0)" ::: "memory");   // wave-local LDS only

    float b2f[8];
    #pragma unroll
    for (int nt = 0; nt < 8; nt++) b2f[nt] = b2[nt * 16 + l15];

    const int tbase = (blockIdx.x * 4 + wave) * 4;

    #pragma unroll
    for (int mt = 0; mt < 4; mt++) {
        const int t = tbase + mt;
        const int rnode = trec[t];               // uniform across wave
        if (rnode < 0) continue;                 // dead tail tile

        // receiver-side row (uniform; L1/L2-hot since adjacent tiles share it)
        bf16x8 gb[4];
        #pragma unroll
        for (int ks = 0; ks < 4; ks++)
            gb[ks] = *(const bf16x8*)(G + (size_t)rnode * 256 + 128 + ks * 32 + quad * 8);
        float rx = coords[3 * rnode + 0];
        float ry = coords[3 * rnode + 1];
        float rz = coords[3 * rnode + 2];

        // this tile's 16 slots (replicated across quads)
        int sraw = ssr[t * 16 + l15];
        unsigned long long bal = __ballot(sraw >= 0);    // bits 0..15 = row validity
        int sc = sraw >= 0 ? sraw : rnode;               // clamp sentinel to cached row

        bf16x8 ga[4];
        #pragma unroll
        for (int ks = 0; ks < 4; ks++)
            ga[ks] = *(const bf16x8*)(G + (size_t)sc * 256 + ks * 32 + quad * 8);
        float dx = coords[3 * sc + 0] - rx;
        float dy = coords[3 * sc + 1] - ry;
        float dz = coords[3 * sc + 2] - rz;
        float dist = sqrtf(dx * dx + dy * dy + dz * dz);

        // layer-1 epilogue in A-frag layout (w1c from LDS, quad-broadcast)
        bf16x8 m1f[4];
        #pragma unroll
        for (int ks = 0; ks < 4; ks++) {
            f32x4 c0 = *(const f32x4*)&w1c_s[wave][ks * 32 + quad * 8];
            f32x4 c1 = *(const f32x4*)&w1c_s[wave][ks * 32 + quad * 8 + 4];
            #pragma unroll
            for (int j = 0; j < 4; j++) {
                float pre0 = bf2f(ga[ks][j])     + bf2f(gb[ks][j])     + dist * c0[j];
                float pre1 = bf2f(ga[ks][4 + j]) + bf2f(gb[ks][4 + j]) + dist * c1[j];
                m1f[ks][j]     = f2bf(fast_silu(pre0));
                m1f[ks][4 + j] = f2bf(fast_silu(pre1));
            }
        }

        // layer 2: W2 MFMA
        f32x4 sv[8];
        #pragma unroll
        for (int nt = 0; nt < 8; nt++) sv[nt] = f32x4{0.f, 0.f, 0.f, 0.f};
        #pragma unroll
        for (int ks = 0; ks < 4; ks++)
            #pragma unroll
            for (int nt = 0; nt < 8; nt++)
                sv[nt] = __builtin_amdgcn_mfma_f32_16x16x32_bf16(
                    m1f[ks], w2_pack[(nt * 4 + ks) * 64 + lane], sv[nt], 0, 0, 0);

        // silu + validity-masked row accumulate (C row = quad*4+r)
        float acc[8];
        #pragma unroll
        for (int nt = 0; nt < 8; nt++) acc[nt] = 0.f;
        #pragma unroll
        for (int nt = 0; nt < 8; nt++) {
            #pragma unroll
            for (int r = 0; r < 4; r++) {
                float v = fast_silu(sv[nt][r] + b2f[nt]);
                acc[nt] += ((bal >> (quad * 4 + r)) & 1ull) ? v : 0.f;
            }
        }

        // cross-quad reduce; unconditional full-row atomic flush (512 B / tile)
        #pragma unroll
        for (int nt = 0; nt < 8; nt++) {
            float s = acc[nt];
            s += __shfl_xor(s, 16);
            s += __shfl_xor(s, 32);
            acc[nt] = s;
        }
        size_t base = (size_t)rnode * DD + l15;
        unsafeAtomicAdd(&agg[base + (quad * 2 + 0) * 16], acc[quad * 2 + 0]);
        unsafeAtomicAdd(&agg[base + (quad * 2 + 1) * 16], acc[quad * 2 + 1]);
    }
}

// ---- node kernel: out = h + U2*silu(U1a*h + U1b*agg + c1) + c2 ----
__global__ __launch_bounds__(256, 4) void node_kernel(
    const unsigned short* __restrict__ hp,
    const float* __restrict__ hf,
    const float* __restrict__ agg,
    const bf16x8* __restrict__ u1a_pack,
    const bf16x8* __restrict__ u1b_pack,
    const bf16x8* __restrict__ u2_pack,
    const float* __restrict__ c1,
    const float* __restrict__ c2,
    float* __restrict__ out)
{
    __shared__ unsigned short u1s[4][16][136];

    const int tid = threadIdx.x;
    const int wave = tid >> 6, lane = tid & 63;
    const int quad = lane >> 4, l15 = lane & 15;
    const int nbase = blockIdx.x * 64 + wave * 16;

    int n = nbase + l15;
    int nrow = n < NN ? n : NN - 1;

    float c1v[8];
    #pragma unroll
    for (int nt = 0; nt < 8; nt++) c1v[nt] = c1[nt * 16 + l15];

    bf16x8 ah[4], ag[4];
    #pragma unroll
    for (int ks = 0; ks < 4; ks++) {
        ah[ks] = *(const bf16x8*)(hp + (size_t)nrow * DD + ks * 32 + quad * 8);
        const float* ap = agg + (size_t)nrow * DD + ks * 32 + quad * 8;
        f32x4 g0 = *(const f32x4*)ap;
        f32x4 g1 = *(const f32x4*)(ap + 4);
        bf16x8 t;
        t[0] = f2bf(g0[0]); t[1] = f2bf(g0[1]); t[2] = f2bf(g0[2]); t[3] = f2bf(g0[3]);
        t[4] = f2bf(g1[0]); t[5] = f2bf(g1[1]); t[6] = f2bf(g1[2]); t[7] = f2bf(g1[3]);
        ag[ks] = t;
    }

    f32x4 acc[8];
    #pragma unroll
    for (int nt = 0; nt < 8; nt++) acc[nt] = f32x4{0.f, 0.f, 0.f, 0.f};

    #pragma unroll
    for (int ks = 0; ks < 4; ks++) {
        #pragma unroll
        for (int nt = 0; nt < 8; nt++)
            acc[nt] = __builtin_amdgcn_mfma_f32_16x16x32_bf16(
                ah[ks], u1a_pack[(nt * 4 + ks) * 64 + lane], acc[nt], 0, 0, 0);
        #pragma unroll
        for (int nt = 0; nt < 8; nt++)
            acc[nt] = __builtin_amdgcn_mfma_f32_16x16x32_bf16(
                ag[ks], u1b_pack[(nt * 4 + ks) * 64 + lane], acc[nt], 0, 0, 0);
    }

    #pragma unroll
    for (int nt = 0; nt < 8; nt++) {
        int d = nt * 16 + l15;
        #pragma unroll
        for (int r = 0; r < 4; r++) {
            float pre = acc[nt][r] + c1v[nt];
            u1s[wave][quad * 4 + r][d] = (unsigned short)f2bf(fast_silu(pre));
        }
    }
    asm volatile("s_waitcnt lgkmcnt(0)" ::: "memory");

    bf16x8 a2[4];
    #pragma unroll
    for (int ks = 0; ks < 4; ks++)
        a2[ks] = *(const bf16x8*)(&u1s[wave][l15][ks * 32 + quad * 8]);

    f32x4 acc2[8];
    #pragma unroll
    for (int nt = 0; nt < 8; nt++) acc2[nt] = f32x4{0.f, 0.f, 0.f, 0.f};

    #pragma unroll
    for (int ks = 0; ks < 4; ks++)
        #pragma unroll
        for (int nt = 0; nt < 8; nt++)
            acc2[nt] = __builtin_amdgcn_mfma_f32_16x16x32_bf16(
                a2[ks], u2_pack[(nt * 4 + ks) * 64 + lane], acc2[nt], 0, 0, 0);

    #pragma unroll
    for (int nt = 0; nt < 8; nt++) {
        int d = nt * 16 + l15;
        float c2v = c2[d];
        #pragma unroll
        for (int r = 0; r < 4; r++) {
            int n2 = nbase + quad * 4 + r;
            if (n2 < NN) {
                size_t idx = (size_t)n2 * DD + d;
                out[idx] = hf[idx] + acc2[nt][r] + c2v;
            }
        }
    }
}

extern "C" void kernel_launch(void* const* d_in, const int* in_sizes, int n_in,
                              void* d_out, int out_size, void* d_ws, size_t ws_size,
                              hipStream_t stream) {
    const float* h      = (const float*)d_in[0];
    const float* coords = (const float*)d_in[1];
    const int* ei       = (const int*)d_in[2];   // int64 in reference -> int32 from harness
    const float* W1 = (const float*)d_in[3];
    const float* b1 = (const float*)d_in[4];
    const float* W2 = (const float*)d_in[5];
    const float* b2 = (const float*)d_in[6];
    const float* U1 = (const float*)d_in[7];
    const float* c1 = (const float*)d_in[8];
    const float* U2 = (const float*)d_in[9];
    const float* c2 = (const float*)d_in[10];
    float* out = (float*)d_out;

    char* ws = (char*)d_ws;
    float* agg            = (float*)ws;                          // 25,600,000 B fp32 [NN][128]
    unsigned short* hp    = (unsigned short*)(ws + 25600000);    // 12,800,000 B bf16 h
    unsigned short* packs = (unsigned short*)(ws + 38400000);    //    196,608 B packed weights
    float* w1c            = (float*)(ws + 38600000);             //        512 B
    unsigned short* G     = (unsigned short*)(ws + 38700000);    // 25,600,000 B bf16 [NN][256]
    int* cnt              = (int*)(ws + 64300000);               //    200,000 B
    int* cursor           = (int*)(ws + 64500000);               //    200,000 B (padded starts)
    int* trec             = (int*)(ws + 64700000);               //    387,520 B tile->receiver
    int* ssr              = (int*)(ws + 65100000);               //  6,200,000 B padded senders
    const bf16x8* w1a = (const bf16x8*)(packs);
    const bf16x8* w1b = (const bf16x8*)(packs + 16384);
    const bf16x8* w2p = (const bf16x8*)(packs + 32768);
    const bf16x8* u1a = (const bf16x8*)(packs + 49152);
    const bf16x8* u1b = (const bf16x8*)(packs + 65536);
    const bf16x8* u2p = (const bf16x8*)(packs + 81920);

    hipMemsetAsync(cnt, 0, NN * sizeof(int), stream);
    hipMemsetAsync(trec, 0xFF, NTILES_MAX * sizeof(int), stream);           // -1
    hipMemsetAsync(ssr, 0xFF, 1550000 * sizeof(int), stream);               // -1 sentinels
    prep_all_kernel<<<6635, 256, 0, stream>>>(h, hp, (float4*)agg, ei, cnt,
                                              W1, W2, U1, U2, packs, w1c);
    scan_kernel<<<1, 1024, 0, stream>>>(cnt, cursor, trec);
    prep_g_scatter_kernel<<<3907, 256, 0, stream>>>(hp, w1a, w1b, b1, G, ei,
                                                    cursor, ssr);
    // edge: 6055 blocks * 4 waves * 4 tiles = 96880 tile slots (>= actual tiles)
    edge_kernel<<<6055, 256, 0, stream>>>(G, coords, ssr, trec, w2p, w1c, b2, agg);
    node_kernel<<<(NN + 63) / 64, 256, 0, stream>>>(hp, h, agg, u1a, u1b, u2p, c1, c2, out);
}

// Round 9
// 431.653 us; speedup vs baseline: 4.0256x; 1.1083x over previous
//
#include <hip/hip_runtime.h>
#include <hip/hip_bf16.h>

#define NN 50000
#define EE 800000
#define DD 128
#define NTILES_MAX 96880          // 6055 blocks * 16 tiles; >= (EE + 15*NN)/16

typedef __attribute__((ext_vector_type(8))) short bf16x8;
typedef __attribute__((ext_vector_type(4))) float f32x4;

__device__ __forceinline__ short f2bf(float f) {
    __hip_bfloat16 h = __float2bfloat16(f);
    return __builtin_bit_cast(short, h);
}

__device__ __forceinline__ float bf2f(short s) {
    unsigned int u = ((unsigned int)(unsigned short)s) << 16;
    return __builtin_bit_cast(float, u);
}

// fast silu: v_rcp_f32 instead of the ~10-instr exact-div sequence.
// rcp error ~1 ulp — far below bf16 rounding already in the pipeline.
__device__ __forceinline__ float fast_silu(float x) {
    return x * __builtin_amdgcn_rcpf(1.0f + __expf(-x));
}

// ---- prep_all: blocks [0,6250): h->bf16, zero agg, receiver histogram.
//      blocks [6250,6635): pack 6 weight blocks into MFMA B-frag order + w1c. ----
__global__ void prep_all_kernel(const float* __restrict__ h, unsigned short* __restrict__ hp,
                                float4* __restrict__ agg4, const int* __restrict__ ei,
                                int* __restrict__ cnt,
                                const float* __restrict__ W1, const float* __restrict__ W2,
                                const float* __restrict__ U1, const float* __restrict__ U2,
                                unsigned short* __restrict__ packs,
                                float* __restrict__ w1c_out) {
    if (blockIdx.x < 6250) {
        int t = blockIdx.x * blockDim.x + threadIdx.x;   // 1.6M threads exactly
        float4 v = ((const float4*)h)[t];
        ushort4 o;
        o.x = (unsigned short)f2bf(v.x);
        o.y = (unsigned short)f2bf(v.y);
        o.z = (unsigned short)f2bf(v.z);
        o.w = (unsigned short)f2bf(v.w);
        ((ushort4*)hp)[t] = o;
        agg4[t] = make_float4(0.f, 0.f, 0.f, 0.f);       // 6.4M floats exactly
        if (t < EE) atomicAdd(&cnt[ei[EE + t]], 1);      // receiver histogram
        return;
    }
    int t = (blockIdx.x - 6250) * blockDim.x + threadIdx.x;
    if (t >= 98304) {
        if (t < 98432) { int d = t - 98304; w1c_out[d] = W1[d * 257 + 256]; }
        return;
    }
    int mat = t >> 14;
    int r = t & 16383;
    int j = r & 7;
    int lane = (r >> 3) & 63;
    int f = r >> 9;            // 0..31
    int ks = f & 3, nt = f >> 2;
    int n = nt * 16 + (lane & 15);
    int k = ks * 32 + (lane >> 4) * 8 + j;
    float v;
    switch (mat) {
        case 0: v = W1[n * 257 + k];        break;  // W1a (vs h_sender)
        case 1: v = W1[n * 257 + 128 + k];  break;  // W1b (vs h_receiver)
        case 2: v = W2[n * 128 + k];        break;  // W2
        case 3: v = U1[n * 256 + k];        break;  // U1a (vs h)
        case 4: v = U1[n * 256 + 128 + k];  break;  // U1b (vs agg)
        default: v = U2[n * 128 + k];       break;  // U2
    }
    packs[t] = (unsigned short)f2bf(v);
}

// ---- scan: PADDED exclusive scan (buckets rounded to x16), coalesced stripes.
//      Writes off[] (stable starts) and cursor[] (scatter bump). trec fill is
//      done in parallel elsewhere (was the serial tail of this 1-block kernel). ----
__global__ void scan_kernel(const int* __restrict__ cnt, int* __restrict__ off,
                            int* __restrict__ cursor) {
    __shared__ int part[1024];
    const int t = threadIdx.x;
    int s = 0;
    #pragma unroll
    for (int j = 0; j < 49; j++) {
        int i = j * 1024 + t;                        // coalesced
        if (i < NN) s += ((cnt[i] + 15) >> 4) << 4;  // padded size
    }
    part[t] = s;
    __syncthreads();
    for (int d = 1; d < 1024; d <<= 1) {
        int v = (t >= d) ? part[t - d] : 0;
        __syncthreads();
        part[t] += v;
        __syncthreads();
    }
    int base = (t == 0) ? 0 : part[t - 1];
    #pragma unroll
    for (int j = 0; j < 49; j++) {
        int i = j * 1024 + t;                        // coalesced
        if (i < NN) {
            off[i] = base;
            cursor[i] = base;
            base += ((cnt[i] + 15) >> 4) << 4;
        }
    }
}

// ---- prep_g (blocks [0,782)) + scatter (blocks [782,3907)) + trec fill [3907,4103) ----
__global__ __launch_bounds__(256, 2) void prep_g_scatter_kernel(
    const unsigned short* __restrict__ hp,
    const bf16x8* __restrict__ w1a_pack,
    const bf16x8* __restrict__ w1b_pack,
    const float* __restrict__ b1,
    unsigned short* __restrict__ G,
    const int* __restrict__ ei,
    const int* __restrict__ off,
    const int* __restrict__ cnt,
    int* __restrict__ cursor,
    int* __restrict__ ssr,
    int* __restrict__ trec)
{
    if (blockIdx.x >= 3907) {
        // parallel tile->receiver map fill (reads off/cnt only; no cursor race)
        int i = (blockIdx.x - 3907) * 256 + threadIdx.x;   // 50176 threads
        if (i < NN) {
            int tb = off[i] >> 4;
            int ntt = (cnt[i] + 15) >> 4;
            for (int k = 0; k < ntt; k++) trec[tb + k] = i;
        }
        return;
    }
    if (blockIdx.x >= 782) {
        // scatter sender ids into padded receiver buckets (4B random RMW)
        int e = (blockIdx.x - 782) * 256 + threadIdx.x;   // 3125*256 = 800000 exactly
        int s = ei[e], r = ei[EE + e];
        int pos = atomicAdd(&cursor[r], 1);
        ssr[pos] = s;
        return;
    }
    const int tid = threadIdx.x;
    const int wave = tid >> 6, lane = tid & 63;
    const int quad = lane >> 4, l15 = lane & 15;
    const int nbase = blockIdx.x * 64 + wave * 16;

    int n = nbase + l15;
    int nrow = n < NN ? n : NN - 1;

    bf16x8 ah[4];
    #pragma unroll
    for (int ks = 0; ks < 4; ks++)
        ah[ks] = *(const bf16x8*)(hp + (size_t)nrow * DD + ks * 32 + quad * 8);

    f32x4 acca[8], accb[8];
    #pragma unroll
    for (int nt = 0; nt < 8; nt++) {
        acca[nt] = f32x4{0.f, 0.f, 0.f, 0.f};
        accb[nt] = f32x4{0.f, 0.f, 0.f, 0.f};
    }

    #pragma unroll
    for (int ks = 0; ks < 4; ks++) {
        #pragma unroll
        for (int nt = 0; nt < 8; nt++)
            acca[nt] = __builtin_amdgcn_mfma_f32_16x16x32_bf16(
                ah[ks], w1a_pack[(nt * 4 + ks) * 64 + lane], acca[nt], 0, 0, 0);
        #pragma unroll
        for (int nt = 0; nt < 8; nt++)
            accb[nt] = __builtin_amdgcn_mfma_f32_16x16x32_bf16(
                ah[ks], w1b_pack[(nt * 4 + ks) * 64 + lane], accb[nt], 0, 0, 0);
    }

    #pragma unroll
    for (int nt = 0; nt < 8; nt++) {
        int d = nt * 16 + l15;
        float b1v = b1[d];
        #pragma unroll
        for (int r = 0; r < 4; r++) {
            int n2 = nbase + quad * 4 + r;
            if (n2 < NN) {
                G[(size_t)n2 * 256 + d]       = (unsigned short)f2bf(acca[nt][r] + b1v);
                G[(size_t)n2 * 256 + 128 + d] = (unsigned short)f2bf(accb[nt][r]);
            }
        }
    }
}

// ---- edge kernel v8: PADDED-TILE (static loops, spill-free) + fast silu +
//      fma-mask accumulate + occupancy 4 blocks/CU. One full-row atomic flush
//      per tile. ----
__global__ __launch_bounds__(256, 4) void edge_kernel(
    const unsigned short* __restrict__ G,      // [NN][256] bf16: [G1a+b1 | G1b]
    const float* __restrict__ coords,          // [NN][3] (L2-resident, 600 KB)
    const int* __restrict__ ssr,               // [padded slots] sender or -1
    const int* __restrict__ trec,              // [NTILES_MAX] receiver or -1
    const bf16x8* __restrict__ w2_pack,        // 32 KB
    const float* __restrict__ w1c,             // [128] fp32, k-order
    const float* __restrict__ b2,
    float* __restrict__ agg)                   // [NN][128] fp32, pre-zeroed
{
    __shared__ float w1c_s[4][128];

    const int tid = threadIdx.x;
    const int wave = tid >> 6, lane = tid & 63;
    const int quad = lane >> 4, l15 = lane & 15;

    w1c_s[wave][lane] = w1c[lane];
    w1c_s[wave][64 + lane] = w1c[64 + lane];
    asm volatile("s_waitcnt lgkmcnt(0)" ::: "memory");   // wave-local LDS only

    float b2f[8];
    #pragma unroll
    for (int nt = 0; nt < 8; nt++) b2f[nt] = b2[nt * 16 + l15];

    const int tbase = (blockIdx.x * 4 + wave) * 4;

    #pragma unroll
    for (int mt = 0; mt < 4; mt++) {
        const int t = tbase + mt;
        const int rnode = trec[t];               // uniform across wave
        if (rnode < 0) continue;                 // dead tail tile

        // receiver-side row (uniform; L1/L2-hot since adjacent tiles share it)
        bf16x8 gb[4];
        #pragma unroll
        for (int ks = 0; ks < 4; ks++)
            gb[ks] = *(const bf16x8*)(G + (size_t)rnode * 256 + 128 + ks * 32 + quad * 8);
        float rx = coords[3 * rnode + 0];
        float ry = coords[3 * rnode + 1];
        float rz = coords[3 * rnode + 2];

        // this tile's 16 slots (replicated across quads)
        int sraw = ssr[t * 16 + l15];
        unsigned long long bal = __ballot(sraw >= 0);    // bits 0..15 = row validity
        int sc = sraw >= 0 ? sraw : rnode;               // clamp sentinel to cached row

        bf16x8 ga[4];
        #pragma unroll
        for (int ks = 0; ks < 4; ks++)
            ga[ks] = *(const bf16x8*)(G + (size_t)sc * 256 + ks * 32 + quad * 8);
        float dx = coords[3 * sc + 0] - rx;
        float dy = coords[3 * sc + 1] - ry;
        float dz = coords[3 * sc + 2] - rz;
        float dist = sqrtf(dx * dx + dy * dy + dz * dz);

        // validity as 0/1 floats (4 cndmask once, then pure fma in the hot sum)
        float mk[4];
        #pragma unroll
        for (int r = 0; r < 4; r++)
            mk[r] = ((bal >> (quad * 4 + r)) & 1ull) ? 1.f : 0.f;

        // layer-1 epilogue in A-frag layout (w1c from LDS, quad-broadcast)
        bf16x8 m1f[4];
        #pragma unroll
        for (int ks = 0; ks < 4; ks++) {
            f32x4 c0 = *(const f32x4*)&w1c_s[wave][ks * 32 + quad * 8];
            f32x4 c1 = *(const f32x4*)&w1c_s[wave][ks * 32 + quad * 8 + 4];
            #pragma unroll
            for (int j = 0; j < 4; j++) {
                float pre0 = bf2f(ga[ks][j])     + bf2f(gb[ks][j])     + dist * c0[j];
                float pre1 = bf2f(ga[ks][4 + j]) + bf2f(gb[ks][4 + j]) + dist * c1[j];
                m1f[ks][j]     = f2bf(fast_silu(pre0));
                m1f[ks][4 + j] = f2bf(fast_silu(pre1));
            }
        }

        // layer 2: W2 MFMA
        f32x4 sv[8];
        #pragma unroll
        for (int nt = 0; nt < 8; nt++) sv[nt] = f32x4{0.f, 0.f, 0.f, 0.f};
        #pragma unroll
        for (int ks = 0; ks < 4; ks++)
            #pragma unroll
            for (int nt = 0; nt < 8; nt++)
                sv[nt] = __builtin_amdgcn_mfma_f32_16x16x32_bf16(
                    m1f[ks], w2_pack[(nt * 4 + ks) * 64 + lane], sv[nt], 0, 0, 0);

        // silu + masked row accumulate via fma (C row = quad*4+r)
        float acc[8];
        #pragma unroll
        for (int nt = 0; nt < 8; nt++) acc[nt] = 0.f;
        #pragma unroll
        for (int nt = 0; nt < 8; nt++) {
            #pragma unroll
            for (int r = 0; r < 4; r++) {
                float v = fast_silu(sv[nt][r] + b2f[nt]);
                acc[nt] = fmaf(v, mk[r], acc[nt]);
            }
        }

        // cross-quad reduce; unconditional full-row atomic flush (512 B / tile)
        #pragma unroll
        for (int nt = 0; nt < 8; nt++) {
            float s = acc[nt];
            s += __shfl_xor(s, 16);
            s += __shfl_xor(s, 32);
            acc[nt] = s;
        }
        size_t base = (size_t)rnode * DD + l15;
        unsafeAtomicAdd(&agg[base + (quad * 2 + 0) * 16], acc[quad * 2 + 0]);
        unsafeAtomicAdd(&agg[base + (quad * 2 + 1) * 16], acc[quad * 2 + 1]);
    }
}

// ---- node kernel: out = h + U2*silu(U1a*h + U1b*agg + c1) + c2 ----
__global__ __launch_bounds__(256, 4) void node_kernel(
    const unsigned short* __restrict__ hp,
    const float* __restrict__ hf,
    const float* __restrict__ agg,
    const bf16x8* __restrict__ u1a_pack,
    const bf16x8* __restrict__ u1b_pack,
    const bf16x8* __restrict__ u2_pack,
    const float* __restrict__ c1,
    const float* __restrict__ c2,
    float* __restrict__ out)
{
    __shared__ unsigned short u1s[4][16][136];

    const int tid = threadIdx.x;
    const int wave = tid >> 6, lane = tid & 63;
    const int quad = lane >> 4, l15 = lane & 15;
    const int nbase = blockIdx.x * 64 + wave * 16;

    int n = nbase + l15;
    int nrow = n < NN ? n : NN - 1;

    float c1v[8];
    #pragma unroll
    for (int nt = 0; nt < 8; nt++) c1v[nt] = c1[nt * 16 + l15];

    bf16x8 ah[4], ag[4];
    #pragma unroll
    for (int ks = 0; ks < 4; ks++) {
        ah[ks] = *(const bf16x8*)(hp + (size_t)nrow * DD + ks * 32 + quad * 8);
        const float* ap = agg + (size_t)nrow * DD + ks * 32 + quad * 8;
        f32x4 g0 = *(const f32x4*)ap;
        f32x4 g1 = *(const f32x4*)(ap + 4);
        bf16x8 t;
        t[0] = f2bf(g0[0]); t[1] = f2bf(g0[1]); t[2] = f2bf(g0[2]); t[3] = f2bf(g0[3]);
        t[4] = f2bf(g1[0]); t[5] = f2bf(g1[1]); t[6] = f2bf(g1[2]); t[7] = f2bf(g1[3]);
        ag[ks] = t;
    }

    f32x4 acc[8];
    #pragma unroll
    for (int nt = 0; nt < 8; nt++) acc[nt] = f32x4{0.f, 0.f, 0.f, 0.f};

    #pragma unroll
    for (int ks = 0; ks < 4; ks++) {
        #pragma unroll
        for (int nt = 0; nt < 8; nt++)
            acc[nt] = __builtin_amdgcn_mfma_f32_16x16x32_bf16(
                ah[ks], u1a_pack[(nt * 4 + ks) * 64 + lane], acc[nt], 0, 0, 0);
        #pragma unroll
        for (int nt = 0; nt < 8; nt++)
            acc[nt] = __builtin_amdgcn_mfma_f32_16x16x32_bf16(
                ag[ks], u1b_pack[(nt * 4 + ks) * 64 + lane], acc[nt], 0, 0, 0);
    }

    #pragma unroll
    for (int nt = 0; nt < 8; nt++) {
        int d = nt * 16 + l15;
        #pragma unroll
        for (int r = 0; r < 4; r++) {
            float pre = acc[nt][r] + c1v[nt];
            u1s[wave][quad * 4 + r][d] = (unsigned short)f2bf(fast_silu(pre));
        }
    }
    asm volatile("s_waitcnt lgkmcnt(0)" ::: "memory");

    bf16x8 a2[4];
    #pragma unroll
    for (int ks = 0; ks < 4; ks++)
        a2[ks] = *(const bf16x8*)(&u1s[wave][l15][ks * 32 + quad * 8]);

    f32x4 acc2[8];
    #pragma unroll
    for (int nt = 0; nt < 8; nt++) acc2[nt] = f32x4{0.f, 0.f, 0.f, 0.f};

    #pragma unroll
    for (int ks = 0; ks < 4; ks++)
        #pragma unroll
        for (int nt = 0; nt < 8; nt++)
            acc2[nt] = __builtin_amdgcn_mfma_f32_16x16x32_bf16(
                a2[ks], u2_pack[(nt * 4 + ks) * 64 + lane], acc2[nt], 0, 0, 0);

    #pragma unroll
    for (int nt = 0; nt < 8; nt++) {
        int d = nt * 16 + l15;
        float c2v = c2[d];
        #pragma unroll
        for (int r = 0; r < 4; r++) {
            int n2 = nbase + quad * 4 + r;
            if (n2 < NN) {
                size_t idx = (size_t)n2 * DD + d;
                out[idx] = hf[idx] + acc2[nt][r] + c2v;
            }
        }
    }
}

extern "C" void kernel_launch(void* const* d_in, const int* in_sizes, int n_in,
                              void* d_out, int out_size, void* d_ws, size_t ws_size,
                              hipStream_t stream) {
    const float* h      = (const float*)d_in[0];
    const float* coords = (const float*)d_in[1];
    const int* ei       = (const int*)d_in[2];   // int64 in reference -> int32 from harness
    const float* W1 = (const float*)d_in[3];
    const float* b1 = (const float*)d_in[4];
    const float* W2 = (const float*)d_in[5];
    const float* b2 = (const float*)d_in[6];
    const float* U1 = (const float*)d_in[7];
    const float* c1 = (const float*)d_in[8];
    const float* U2 = (const float*)d_in[9];
    const float* c2 = (const float*)d_in[10];
    float* out = (float*)d_out;

    char* ws = (char*)d_ws;
    float* agg            = (float*)ws;                          // 25,600,000 B fp32 [NN][128]
    unsigned short* hp    = (unsigned short*)(ws + 25600000);    // 12,800,000 B bf16 h
    unsigned short* packs = (unsigned short*)(ws + 38400000);    //    196,608 B packed weights
    float* w1c            = (float*)(ws + 38600000);             //        512 B
    unsigned short* G     = (unsigned short*)(ws + 38700000);    // 25,600,000 B bf16 [NN][256]
    int* cnt              = (int*)(ws + 64300000);               //    200,000 B
    int* off              = (int*)(ws + 64500000);               //    200,000 B padded starts
    int* cursor           = (int*)(ws + 64700000);               //    200,000 B scatter cursor
    int* trec             = (int*)(ws + 64900000);               //    387,520 B tile->receiver
    int* ssr              = (int*)(ws + 65300000);               //  6,200,000 B padded senders
    const bf16x8* w1a = (const bf16x8*)(packs);
    const bf16x8* w1b = (const bf16x8*)(packs + 16384);
    const bf16x8* w2p = (const bf16x8*)(packs + 32768);
    const bf16x8* u1a = (const bf16x8*)(packs + 49152);
    const bf16x8* u1b = (const bf16x8*)(packs + 65536);
    const bf16x8* u2p = (const bf16x8*)(packs + 81920);

    hipMemsetAsync(cnt, 0, NN * sizeof(int), stream);
    hipMemsetAsync(trec, 0xFF, NTILES_MAX * sizeof(int), stream);           // -1
    hipMemsetAsync(ssr, 0xFF, 1550000 * sizeof(int), stream);               // -1 sentinels
    prep_all_kernel<<<6635, 256, 0, stream>>>(h, hp, (float4*)agg, ei, cnt,
                                              W1, W2, U1, U2, packs, w1c);
    scan_kernel<<<1, 1024, 0, stream>>>(cnt, off, cursor);
    prep_g_scatter_kernel<<<4103, 256, 0, stream>>>(hp, w1a, w1b, b1, G, ei,
                                                    off, cnt, cursor, ssr, trec);
    // edge: 6055 blocks * 4 waves * 4 tiles = 96880 tile slots (>= actual tiles)
    edge_kernel<<<6055, 256, 0, stream>>>(G, coords, ssr, trec, w2p, w1c, b2, agg);
    node_kernel<<<(NN + 63) / 64, 256, 0, stream>>>(hp, h, agg, u1a, u1b, u2p, c1, c2, out);
}